// Round 2
// baseline (78.737 us; speedup 1.0000x reference)
//
#include <hip/hip_runtime.h>

// GravityMCDecoder: per-edge pairwise-distance decoder.
// d2(u,v) is symmetric -> one 64-dim squared distance per edge feeds both
// logits. Two kernels:
//   1) repack z[12288][65] -> zp[12288][68]  (272 B row stride, 16B-aligned,
//      enables global_load_dwordx4 gathers; 65*4=260 B isn't even 8B-aligned)
//   2) gather: 16 lanes/edge, one float4 load per row per lane, butterfly
//      reduce, leader computes log/sigmoid tail and stores one float4.

constexpr int kNodes = 12288;
constexpr int kD     = 64;     // D_PLUS_1 - 1
constexpr int kRowIn = 65;     // input row stride (floats)
constexpr int kRowP  = 68;     // padded row stride (floats) = 272 B, 16B mult
constexpr int kEdges = 262144;
constexpr float kEps = 0.01f;

__global__ __launch_bounds__(256) void repack_kernel(
    const float* __restrict__ z, float* __restrict__ zp)
{
    const int i = blockIdx.x * 256 + threadIdx.x;
    if (i < kNodes * kRowIn) {
        const int row = i / kRowIn;          // compiler magic-mul
        const int col = i - row * kRowIn;
        zp[row * kRowP + col] = z[i];
    }
}

__global__ __launch_bounds__(256) void edge_kernel(
    const float* __restrict__ zp,
    const float* __restrict__ lptr,
    const int*   __restrict__ eidx,   // [2, kEdges]: u's then v's
    float4*      __restrict__ out)    // [kEdges] = (p_nb, p_pu, p_pb, p_nu)
{
    const int tid = blockIdx.x * 256 + threadIdx.x;
    const int e   = tid >> 4;         // one edge per 16-lane group, no loop
    const int sub = tid & 15;

    const int u = eidx[e];            // same addr across 16 lanes: broadcast
    const int v = eidx[kEdges + e];
    const float l = lptr[0];

    const float* ru = zp + u * kRowP;
    const float* rv = zp + v * kRowP;

    // m loads issue before the row gathers; latency hides under them.
    const float mu = ru[kD];
    const float mv = rv[kD];

    // Lane sub covers dims [4*sub, 4*sub+3]; 16 lanes span the full 256 B row.
    const float4 a = *(const float4*)(ru + sub * 4);
    const float4 b = *(const float4*)(rv + sub * 4);

    float p;
    {
        const float dx = a.x - b.x, dy = a.y - b.y;
        const float dz = a.z - b.z, dw = a.w - b.w;
        p = fmaf(dx, dx, fmaf(dy, dy, fmaf(dz, dz, dw * dw)));
    }
    // butterfly sum across the 16-lane group (masks < 16 stay in-group)
    p += __shfl_xor(p, 1);
    p += __shfl_xor(p, 2);
    p += __shfl_xor(p, 4);
    p += __shfl_xor(p, 8);

    if (sub == 0) {
        const float logd = __logf(p + kEps);
        const float luv  = mv - l * logd;   // adj[u,v] = m[v] - l*log r2
        const float lvu  = mu - l * logd;   // adj[v,u] = m[u] - l*log r2
        const float suv  = 1.f / (1.f + __expf(-luv));
        const float svu  = 1.f / (1.f + __expf(-lvu));
        out[e] = make_float4((1.f - suv) * (1.f - svu),   // p_nb
                             suv         * (1.f - svu),   // p_pu
                             suv         * svu,           // p_pb
                             (1.f - suv) * svu);          // p_nu
    }
}

extern "C" void kernel_launch(void* const* d_in, const int* in_sizes, int n_in,
                              void* d_out, int out_size, void* d_ws, size_t ws_size,
                              hipStream_t stream) {
    const float* z    = (const float*)d_in[0];
    const float* lptr = (const float*)d_in[1];
    const int*   eidx = (const int*)d_in[2];
    float*       zp   = (float*)d_ws;            // 12288*68*4 = 3.34 MB scratch
    float4*      out  = (float4*)d_out;

    const int n_elems = kNodes * kRowIn;
    repack_kernel<<<dim3((n_elems + 255) / 256), dim3(256), 0, stream>>>(z, zp);

    // kEdges edges * 16 lanes / 256 threads = 16384 blocks, one edge per group
    edge_kernel<<<dim3(kEdges * 16 / 256), dim3(256), 0, stream>>>(zp, lptr, eidx, out);
}

// Round 3
// 73.295 us; speedup vs baseline: 1.0743x; 1.0743x over previous
//
#include <hip/hip_runtime.h>

// GravityMCDecoder: per-edge pairwise-distance decoder.
// Reference builds the full 12288^2 adjacency then gathers 262144 edges; we
// compute only what's needed: d2(u,v) is symmetric, so one 64-dim squared
// distance per edge feeds both logits.
//
// Single kernel (R2 showed a second launch costs ~+6 us in the graph, more
// than the repack it paid for). One edge per 16-lane group, NO grid-stride
// loop (R0's 4-iter loop serialized the idx->gather chain: ~25 us vs ~7 us).
// Row stride 65 floats (260 B) is only 4B-aligned, so per-lane scalar dword
// loads; 8 independent loads/lane issue in one memory epoch (ILP hides L2
// latency). The 4 subgroup leaders in a wave hold consecutive e, so their
// exec-masked float4 stores coalesce into one 64 B segment.

constexpr int kD     = 64;     // D_PLUS_1 - 1
constexpr int kRow   = 65;     // row stride of z in floats
constexpr int kEdges = 262144;
constexpr float kEps = 0.01f;

__global__ __launch_bounds__(256) void edge_kernel(
    const float* __restrict__ z,
    const float* __restrict__ lptr,
    const int*   __restrict__ eidx,   // [2, kEdges]: u's then v's
    float4*      __restrict__ out)    // [kEdges] = (p_nb, p_pu, p_pb, p_nu)
{
    const int tid = blockIdx.x * 256 + threadIdx.x;
    const int e   = tid >> 4;         // one edge per 16-lane group
    const int sub = tid & 15;

    const int u = eidx[e];            // 16 lanes share addr -> broadcast line
    const int v = eidx[kEdges + e];
    const float l = lptr[0];

    const float* ru = z + u * kRow;
    const float* rv = z + v * kRow;

    // All 10 loads below are independent -> one memory epoch after idx loads.
    const float mu = ru[kD];
    const float mv = rv[kD];

    const int c = sub * 4;            // lane covers dims [c, c+3]
    float du0 = ru[c]     - rv[c];
    float du1 = ru[c + 1] - rv[c + 1];
    float du2 = ru[c + 2] - rv[c + 2];
    float du3 = ru[c + 3] - rv[c + 3];

    float p = fmaf(du0, du0, fmaf(du1, du1, fmaf(du2, du2, du3 * du3)));

    // butterfly sum across the 16-lane group (masks < 16 stay in-group)
    p += __shfl_xor(p, 1);
    p += __shfl_xor(p, 2);
    p += __shfl_xor(p, 4);
    p += __shfl_xor(p, 8);

    if (sub == 0) {
        const float logd = __logf(p + kEps);
        const float luv  = mv - l * logd;   // adj[u,v] = m[v] - l*log r2
        const float lvu  = mu - l * logd;   // adj[v,u] = m[u] - l*log r2
        const float suv  = 1.f / (1.f + __expf(-luv));
        const float svu  = 1.f / (1.f + __expf(-lvu));
        out[e] = make_float4((1.f - suv) * (1.f - svu),   // p_nb
                             suv         * (1.f - svu),   // p_pu
                             suv         * svu,           // p_pb
                             (1.f - suv) * svu);          // p_nu
    }
}

extern "C" void kernel_launch(void* const* d_in, const int* in_sizes, int n_in,
                              void* d_out, int out_size, void* d_ws, size_t ws_size,
                              hipStream_t stream) {
    const float* z    = (const float*)d_in[0];
    const float* lptr = (const float*)d_in[1];
    const int*   eidx = (const int*)d_in[2];
    float4*      out  = (float4*)d_out;

    // kEdges * 16 lanes / 256 threads = 16384 blocks, one edge per group.
    edge_kernel<<<dim3(kEdges * 16 / 256), dim3(256), 0, stream>>>(z, lptr, eidx, out);
}